// Round 1
// baseline (1143.798 us; speedup 1.0000x reference)
//
#include <hip/hip_runtime.h>
#include <hip/hip_bf16.h>
#include <stdint.h>

// Problem constants (reference: N=4096, D=1024, V=50257)
#define NROWS 4096
#define DDIM  1024
#define VDIM  50257
#define VPAD  50304   // 393 * 128

typedef __bf16 bf16;
typedef __bf16 bf16x4 __attribute__((ext_vector_type(4)));
typedef __bf16 bf16x8 __attribute__((ext_vector_type(8)));
typedef float  f32x4  __attribute__((ext_vector_type(4)));

// ---- async global -> LDS, 16B per lane (dest = wave-uniform base + lane*16) ----
__device__ __forceinline__ void async_load16(const void* gsrc, const void* lds_dst) {
  __builtin_amdgcn_global_load_lds(
      (__attribute__((address_space(1))) unsigned int*)(uintptr_t)gsrc,
      (__attribute__((address_space(3))) unsigned int*)(uint32_t)(uintptr_t)lds_dst,
      16, 0, 0);
}

// ---- fp32 -> bf16 conversion (4 elems/thread); pads beyond n_src with zeros ----
__global__ __launch_bounds__(256)
void cvt_kernel(const float* __restrict__ src, bf16* __restrict__ dst, size_t n_src) {
  size_t i = ((size_t)blockIdx.x * 256 + threadIdx.x) * 4;
  float4 f = make_float4(0.f, 0.f, 0.f, 0.f);
  if (i < n_src) f = *(const float4*)(src + i);
  bf16x4 o = { (__bf16)f.x, (__bf16)f.y, (__bf16)f.z, (__bf16)f.w };
  *(bf16x4*)(dst + i) = o;
}

// ---- exact fp32 target logit: lt[n] = dot(x[n], w[target[n]]) ----
__global__ __launch_bounds__(256)
void tlogit_kernel(const float* __restrict__ x, const float* __restrict__ w,
                   const int* __restrict__ tgt, float* __restrict__ lt) {
  int n = blockIdx.x;
  int t = tgt[n];
  const float4* xr = (const float4*)(x + (size_t)n * DDIM);
  const float4* wr = (const float4*)(w + (size_t)t * DDIM);
  float4 a = xr[threadIdx.x];
  float4 b = wr[threadIdx.x];
  float s = a.x * b.x + a.y * b.y + a.z * b.z + a.w * b.w;
  #pragma unroll
  for (int m = 32; m; m >>= 1) s += __shfl_down(s, m);
  __shared__ float red[4];
  if ((threadIdx.x & 63) == 0) red[threadIdx.x >> 6] = s;
  __syncthreads();
  if (threadIdx.x == 0) lt[n] = red[0] + red[1] + red[2] + red[3];
}

// ---- fused GEMM (bf16 MFMA) + exp + per-row partial sum -> atomicAdd S[n] ----
// Tile: BM=128 (x rows), BN=128 (vocab rows), BK=32. 256 threads = 4 waves (2x2).
// LDS layout per tile: [k-chunk c (0..3)][row r (0..127)] of 16B (8 bf16) slots,
// matching global_load_lds's "uniform base + lane*16" dest constraint AND giving
// 16B-stride (minimal-conflict) ds_read_b128 fragment reads.
__global__ __launch_bounds__(256, 2)
void gemm_lse_kernel(const bf16* __restrict__ xb,   // [NROWS][DDIM]
                     const bf16* __restrict__ wb,   // [VPAD][DDIM] (pad rows zero)
                     float* __restrict__ S) {       // [NROWS] running sum of exp
  __shared__ __align__(16) unsigned char smem[16384];  // A: 0..8K, B: 8K..16K

  const int tid  = threadIdx.x;
  const int wid  = tid >> 6;
  const int lane = tid & 63;
  const int col  = lane & 15;
  const int quad = lane >> 4;

  const int m0 = blockIdx.x * 128;   // row tiles fastest -> weight slab shared in LLC
  const int v0 = blockIdx.y * 128;

  const int wave_m = wid >> 1;  // 0..1
  const int wave_n = wid & 1;   // 0..1

  // Staging: 8 slots-of-64 per tile; wave wid issues insts j=wid and j=wid+4.
  // inst j covers slots j*64+lane: chunk c=j>>1, row r=(j&1)*64+lane.
  const int j0 = wid, j1 = wid + 4;
  const int rA0 = (j0 & 1) * 64 + lane, c0 = j0 >> 1;
  const int rA1 = (j1 & 1) * 64 + lane, c1 = j1 >> 1;

  const bf16* gA0 = xb + (size_t)(m0 + rA0) * DDIM + c0 * 8;
  const bf16* gA1 = xb + (size_t)(m0 + rA1) * DDIM + c1 * 8;
  const bf16* gB0 = wb + (size_t)(v0 + rA0) * DDIM + c0 * 8;
  const bf16* gB1 = wb + (size_t)(v0 + rA1) * DDIM + c1 * 8;

  const unsigned char* ldsA0 = smem + j0 * 1024;
  const unsigned char* ldsA1 = smem + j1 * 1024;
  const unsigned char* ldsB0 = smem + 8192 + j0 * 1024;
  const unsigned char* ldsB1 = smem + 8192 + j1 * 1024;

  // Fragment read offsets: A[m=lane&15][k=quad*8+j], B[n=lane&15][k=quad*8+j]
  uint32_t aoff[4], boff[4];
  #pragma unroll
  for (int i = 0; i < 4; ++i) {
    aoff[i] = (uint32_t)((quad * 128) + wave_m * 64 + i * 16 + col) * 16u;
    boff[i] = 8192u + (uint32_t)((quad * 128) + wave_n * 64 + i * 16 + col) * 16u;
  }

  f32x4 acc[4][4] = {};

  for (int k0 = 0; k0 < DDIM; k0 += 32) {
    async_load16(gA0 + k0, ldsA0);
    async_load16(gA1 + k0, ldsA1);
    async_load16(gB0 + k0, ldsB0);
    async_load16(gB1 + k0, ldsB1);
    __syncthreads();  // drains vmcnt before barrier (compiler-inserted)

    bf16x8 af[4], bfr[4];
    #pragma unroll
    for (int i = 0; i < 4; ++i) af[i]  = *(const bf16x8*)(smem + aoff[i]);
    #pragma unroll
    for (int i = 0; i < 4; ++i) bfr[i] = *(const bf16x8*)(smem + boff[i]);

    #pragma unroll
    for (int mi = 0; mi < 4; ++mi)
      #pragma unroll
      for (int ni = 0; ni < 4; ++ni)
        acc[mi][ni] = __builtin_amdgcn_mfma_f32_16x16x32_bf16(
            af[mi], bfr[ni], acc[mi][ni], 0, 0, 0);

    __syncthreads();  // protect LDS before next stage overwrites
  }

  // Epilogue: exp + row-sum. D layout: row m = quad*4+reg, col n = lane&15.
  const int mbase = m0 + wave_m * 64;
  const int vbase = v0 + wave_n * 64;
  #pragma unroll
  for (int mi = 0; mi < 4; ++mi) {
    #pragma unroll
    for (int r = 0; r < 4; ++r) {
      float p = 0.f;
      #pragma unroll
      for (int ni = 0; ni < 4; ++ni) {
        int v = vbase + ni * 16 + col;
        float e = __expf(acc[mi][ni][r]);
        p += (v < VDIM) ? e : 0.f;   // mask vocab pad
      }
      p += __shfl_xor(p, 8);
      p += __shfl_xor(p, 4);
      p += __shfl_xor(p, 2);
      p += __shfl_xor(p, 1);
      if (col == 0)
        atomicAdd(&S[mbase + mi * 16 + quad * 4 + r], p);
    }
  }
}

// ---- final: loss = mean(log(S[n]) - lt[n]) ----
__global__ __launch_bounds__(256)
void loss_kernel(const float* __restrict__ S, const float* __restrict__ lt,
                 float* __restrict__ out) {
  float s = 0.f;
  for (int n = threadIdx.x; n < NROWS; n += 256)
    s += logf(S[n]) - lt[n];
  #pragma unroll
  for (int m = 32; m; m >>= 1) s += __shfl_down(s, m);
  __shared__ float red[4];
  if ((threadIdx.x & 63) == 0) red[threadIdx.x >> 6] = s;
  __syncthreads();
  if (threadIdx.x == 0)
    out[0] = (red[0] + red[1] + red[2] + red[3]) / (float)NROWS;
}

extern "C" void kernel_launch(void* const* d_in, const int* in_sizes, int n_in,
                              void* d_out, int out_size, void* d_ws, size_t ws_size,
                              hipStream_t stream) {
  const float* x = (const float*)d_in[0];   // [4096,1024] fp32
  const float* w = (const float*)d_in[1];   // [50257,1024] fp32
  const int*   t = (const int*)d_in[2];     // [4096] int
  float* out = (float*)d_out;

  char* ws = (char*)d_ws;
  const size_t wb_bytes = (size_t)VPAD * DDIM * sizeof(bf16);   // 103.0 MB
  const size_t xb_bytes = (size_t)NROWS * DDIM * sizeof(bf16);  //   8.4 MB
  bf16*  wb = (bf16*)ws;
  bf16*  xb = (bf16*)(ws + wb_bytes);
  float* S  = (float*)(ws + wb_bytes + xb_bytes);
  float* lt = S + NROWS;

  if (ws_size < wb_bytes + xb_bytes + 2 * NROWS * sizeof(float)) return; // fail loud

  hipMemsetAsync(S, 0, NROWS * sizeof(float), stream);
  cvt_kernel<<<(VPAD * (DDIM / 4)) / 256, 256, 0, stream>>>(w, wb, (size_t)VDIM * DDIM);
  cvt_kernel<<<(NROWS * (DDIM / 4)) / 256, 256, 0, stream>>>(x, xb, (size_t)NROWS * DDIM);
  tlogit_kernel<<<NROWS, 256, 0, stream>>>(x, w, t, lt);

  dim3 grid(NROWS / 128, VPAD / 128);  // (32, 393), row tiles fastest
  gemm_lse_kernel<<<grid, 256, 0, stream>>>(xb, wb, S);

  loss_kernel<<<1, 256, 0, stream>>>(S, lt, out);
}